// Round 2
// baseline (2791.143 us; speedup 1.0000x reference)
//
#include <hip/hip_runtime.h>
#include <hip/hip_bf16.h>

typedef __hip_bfloat16 bf16;

#define NNODE 10000
#define DDEG  15
#define EE    320
#define LL    16
#define NH    5
#define HD    64
#define OUTD  30
#define PCOLS 1920   // 6*E : [Qin|Kin|Vin|Qout|Kout|Vout]
#define KF    642    // 2*E + 2 (alpha columns)

// ---------------------------------------------------------------------------
// dtype detection: bf16 data -> low-16 exponent field clustered in [100,140];
// f32 data -> low 16 bits are mantissa (uniform) -> ~16% hit rate.
// ---------------------------------------------------------------------------
__global__ void detect_dtype_kernel(const unsigned int* __restrict__ X, int* __restrict__ flag)
{
    __shared__ int cnt;
    if (threadIdx.x == 0) cnt = 0;
    __syncthreads();
    int local = 0;
    for (int i = threadIdx.x; i < 1024; i += 256) {
        unsigned int lo = X[i] & 0xFFFFu;
        int e = (int)((lo >> 7) & 0xFFu);
        if (e >= 100 && e <= 140) local++;
    }
    atomicAdd(&cnt, local);
    __syncthreads();
    if (threadIdx.x == 0) *flag = (cnt > 512) ? 1 : 0;
}

// convert input (bf16 or f32 per flag) to f32
__global__ void convert_kernel(const void* __restrict__ src, float* __restrict__ dst,
                               int n, const int* __restrict__ flag)
{
    int i = blockIdx.x * 256 + threadIdx.x;
    if (i >= n) return;
    if (*flag) dst[i] = __bfloat162float(((const bf16*)src)[i]);
    else       dst[i] = ((const float*)src)[i];
}

__device__ __forceinline__ float cvt(float x) { return x; }
__device__ __forceinline__ float cvt(bf16 x) { return __bfloat162float(x); }
__device__ __forceinline__ void stor(float* p, float v) { *p = v; }
__device__ __forceinline__ void stor(bf16* p, float v) { *p = __float2bfloat16(v); }

// ---------------------------------------------------------------------------
// Generic 64x64 tiled GEMM: C[M,N] = op(A) @ op(B) + bias
// AT: A is [K,M] (k-major). BT: B is [N,K] row-major (transposed).
// ---------------------------------------------------------------------------
template<bool AT, bool BT, typename ATYPE, typename BTYPE, typename OT>
__global__ __launch_bounds__(256) void gemm_k(const ATYPE* __restrict__ A, int lda,
                       const BTYPE* __restrict__ B, int ldb,
                       const float* __restrict__ bias,
                       OT* __restrict__ C, int ldc, int M, int Nn, int K)
{
    __shared__ float As[16][65];
    __shared__ float Bs[16][65];
    const int tid = threadIdx.x;
    const int tx = tid & 15, ty = tid >> 4;
    const int n0 = blockIdx.x * 64, m0 = blockIdx.y * 64;
    float acc[4][4] = {};
    for (int k0 = 0; k0 < K; k0 += 16) {
        if constexpr (AT) {
            for (int i = tid; i < 1024; i += 256) {
                int kk = i >> 6, r = i & 63;
                int gm = m0 + r, gk = k0 + kk;
                As[kk][r] = (gm < M && gk < K) ? cvt(A[(long)gk * lda + gm]) : 0.f;
            }
        } else {
            for (int i = tid; i < 1024; i += 256) {
                int r = i >> 4, kk = i & 15;
                int gm = m0 + r, gk = k0 + kk;
                As[kk][r] = (gm < M && gk < K) ? cvt(A[(long)gm * lda + gk]) : 0.f;
            }
        }
        if constexpr (BT) {
            for (int i = tid; i < 1024; i += 256) {
                int r = i >> 4, kk = i & 15;
                int gn = n0 + r, gk = k0 + kk;
                Bs[kk][r] = (gn < Nn && gk < K) ? cvt(B[(long)gn * ldb + gk]) : 0.f;
            }
        } else {
            for (int i = tid; i < 1024; i += 256) {
                int kk = i >> 6, c = i & 63;
                int gk = k0 + kk, gn = n0 + c;
                Bs[kk][c] = (gk < K && gn < Nn) ? cvt(B[(long)gk * ldb + gn]) : 0.f;
            }
        }
        __syncthreads();
        #pragma unroll
        for (int kk = 0; kk < 16; ++kk) {
            float ra[4], rb[4];
            #pragma unroll
            for (int a = 0; a < 4; ++a) ra[a] = As[kk][ty * 4 + a];
            #pragma unroll
            for (int b = 0; b < 4; ++b) rb[b] = Bs[kk][tx * 4 + b];
            #pragma unroll
            for (int a = 0; a < 4; ++a)
                #pragma unroll
                for (int b = 0; b < 4; ++b)
                    acc[a][b] += ra[a] * rb[b];
        }
        __syncthreads();
    }
    #pragma unroll
    for (int a = 0; a < 4; ++a) {
        int gm = m0 + ty * 4 + a;
        if (gm >= M) continue;
        #pragma unroll
        for (int b = 0; b < 4; ++b) {
            int gn = n0 + tx * 4 + b;
            if (gn >= Nn) continue;
            float v = acc[a][b] + (bias ? bias[gn] : 0.f);
            stor(&C[(long)gm * ldc + gn], v);
        }
    }
}

// ---------------------------------------------------------------------------
// which: 0->bqc_in 1->bkc_in 2->bkc_out 3->Vcat row640 (bvc_in) 4->Vcat row641
// ---------------------------------------------------------------------------
__global__ __launch_bounds__(320) void compose_bias_kernel(
        const float* __restrict__ in_o_b, const float* __restrict__ out_o_b,
        const float* __restrict__ fin_qkv_w, const float* __restrict__ fin_qkv_b,
        float* __restrict__ bqc_in, float* __restrict__ bkc_in,
        float* __restrict__ bkc_out, float* __restrict__ Vcat)
{
    const int which = blockIdx.x;
    const int b = threadIdx.x;
    const float* ob = (which == 2 || which == 4) ? out_o_b : in_o_b;
    const int off = (which == 0) ? 0 : (which <= 2) ? 320 : 640;
    float acc = fin_qkv_b[off + b];
    const float* wr = fin_qkv_w + (long)(off + b) * EE;
    for (int e = 0; e < EE; ++e) acc += ob[e] * wr[e];
    float* dst = (which == 0) ? bqc_in : (which == 1) ? bkc_in : (which == 2) ? bkc_out
               : (which == 3) ? (Vcat + 640 * EE) : (Vcat + 641 * EE);
    dst[b] = acc;
}

__global__ void compose_bfin(const float* __restrict__ fin_o_b, const float* __restrict__ W,
                             float* __restrict__ bfin)
{
    int j = threadIdx.x;
    if (j >= OUTD) return;
    float acc = 0.f;
    for (int e = 0; e < EE; ++e) acc += fin_o_b[e] * W[e * OUTD + j];
    bfin[j] = acc;
}

// M2[a,c] = sum_b Qc[a,b] * Ktilde(c,b);  bT[c] = sum_b bqc[b] * Ktilde(c,b)
__global__ __launch_bounds__(704) void compose_M2_kernel(
        const float* __restrict__ Qc, const float* __restrict__ bqc,
        const float* __restrict__ Kc_in, const float* __restrict__ Kc_out,
        const float* __restrict__ bkc_in, const float* __restrict__ bkc_out,
        float* __restrict__ M2, float* __restrict__ bT)
{
    const int arow = (int)blockIdx.x - 1;   // -1 -> bias row
    __shared__ float qrow[EE];
    const float* src = (arow < 0) ? bqc : (Qc + (long)arow * EE);
    for (int b = threadIdx.x; b < EE; b += blockDim.x) qrow[b] = src[b];
    __syncthreads();
    const int c = threadIdx.x;
    if (c >= KF) return;
    const float* kr = (c < 320) ? (Kc_in + (long)c * EE)
                    : (c < 640) ? (Kc_out + (long)(c - 320) * EE)
                    : (c == 640) ? bkc_in : bkc_out;
    float acc = 0.f;
    for (int b = 0; b < EE; ++b) acc += qrow[b] * kr[b];
    if (arow < 0) bT[c] = acc;
    else M2[(long)arow * KF + c] = acc;
}

// ---------------------------------------------------------------------------
// Layer-1 attention: one block per (node, dir). Gathers Q/K/V rows of P,
// 5-head 16x16 attention, writes pre-output-projection O [node][dir*16+l][320]
// ---------------------------------------------------------------------------
__global__ __launch_bounds__(256) void attn1_kernel(const bf16* __restrict__ P,
                const int* __restrict__ in_idx, const int* __restrict__ out_idx,
                bf16* __restrict__ O, int node_base, int node_cnt)
{
    const int bx = blockIdx.x;
    const int lnode = bx >> 1, dir = bx & 1;
    const int node = node_base + lnode;
    const int tid = threadIdx.x;
    __shared__ float q_s[LL][EE + 1], k_s[LL][EE + 1], v_s[LL][EE + 1];
    __shared__ float a_s[NH][LL][LL];
    __shared__ int srcs[LL];
    if (tid == 0) srcs[0] = node;
    else if (tid < 16) {
        const int* idx = dir ? out_idx : in_idx;
        srcs[tid] = idx[node * DDEG + tid - 1];
    }
    __syncthreads();
    const int coloff = dir * 960;
    for (int l = 0; l < LL; ++l) {
        long base = (long)srcs[l] * PCOLS + coloff;
        for (int c = tid; c < 960; c += 256) {
            float v = __bfloat162float(P[base + c]);
            if (c < 320) q_s[l][c] = v;
            else if (c < 640) k_s[l][c - 320] = v;
            else v_s[l][c - 640] = v;
        }
    }
    __syncthreads();
    {
        const int l = tid >> 4, m = tid & 15;
        #pragma unroll
        for (int h = 0; h < NH; ++h) {
            float p = 0.f;
            const int off = h * HD;
            for (int d = 0; d < HD; ++d) p += q_s[l][off + d] * k_s[m][off + d];
            a_s[h][l][m] = p * 0.125f;   // 1/sqrt(64)
        }
    }
    __syncthreads();
    if (tid < NH * LL) {
        const int h = tid / 16, l = tid & 15;
        float mx = -1e30f;
        for (int m = 0; m < LL; ++m) mx = fmaxf(mx, a_s[h][l][m]);
        float e[LL], sum = 0.f;
        for (int m = 0; m < LL; ++m) { e[m] = __expf(a_s[h][l][m] - mx); sum += e[m]; }
        float inv = 1.f / sum;
        for (int m = 0; m < LL; ++m) a_s[h][l][m] = e[m] * inv;
    }
    __syncthreads();
    bf16* orow = O + (long)lnode * (32 * EE) + dir * (16 * EE);
    for (int i2 = tid; i2 < 16 * EE; i2 += 256) {
        const int l = i2 / EE, e2 = i2 % EE, h = e2 >> 6;
        float acc = 0.f;
        #pragma unroll
        for (int m = 0; m < LL; ++m) acc += a_s[h][l][m] * v_s[m][e2];
        orow[i2] = __float2bfloat16(acc);
    }
}

// ---------------------------------------------------------------------------
// Final attention: one block per node. s[m] = (o[m]·t_sel + c_sel)/sqrt(320),
// softmax over 32, writes G = [g_in(320) | g_out(320) | a_in | a_out] (bf16)
// ---------------------------------------------------------------------------
__global__ __launch_bounds__(256) void final_attn_kernel(const bf16* __restrict__ O,
                const float* __restrict__ T, bf16* __restrict__ G)
{
    const int i = blockIdx.x;
    const int tid = threadIdx.x;
    __shared__ float o_s[32][EE + 1];
    __shared__ float t_s[KF];
    __shared__ float a_lds[32];
    const bf16* orow = O + (long)i * (32 * EE);
    for (int idx = tid; idx < 32 * EE; idx += 256)
        o_s[idx / EE][idx % EE] = __bfloat162float(orow[idx]);
    for (int c = tid; c < KF; c += 256) t_s[c] = T[(long)i * KF + c];
    __syncthreads();
    {
        const int m = tid >> 3, sub = tid & 7;
        const int hoff = (m < 16) ? 0 : 320;
        float p = 0.f;
        for (int e = sub; e < EE; e += 8) p += o_s[m][e] * t_s[hoff + e];
        p += __shfl_down(p, 4, 8);
        p += __shfl_down(p, 2, 8);
        p += __shfl_down(p, 1, 8);
        if (sub == 0) a_lds[m] = (p + t_s[(m < 16) ? 640 : 641]) * 0.05590169943749474f;
    }
    __syncthreads();
    if (tid < 32) {
        float sv = a_lds[tid];
        float mx = sv;
        for (int o = 16; o > 0; o >>= 1) mx = fmaxf(mx, __shfl_xor(mx, o, 32));
        float e = __expf(sv - mx);
        float sm = e;
        for (int o = 16; o > 0; o >>= 1) sm += __shfl_xor(sm, o, 32);
        a_lds[tid] = e / sm;
    }
    __syncthreads();
    bf16* grow = G + (long)i * KF;
    if (tid < 2) {
        float s = 0.f;
        for (int m = tid * 16; m < tid * 16 + 16; ++m) s += a_lds[m];
        grow[640 + tid] = __float2bfloat16(s);
    }
    for (int idx = tid; idx < 640; idx += 256) {
        const int half = idx / 320, e = idx % 320;
        float g = 0.f;
        #pragma unroll
        for (int m = 0; m < 16; ++m) g += a_lds[half * 16 + m] * o_s[half * 16 + m][e];
        grow[idx] = __float2bfloat16(g);
    }
}

// ---------------------------------------------------------------------------
// out[i,j] = elu( ofin[i,:] @ Wfin[:,j] + bfin[j] ); output dtype per flag
// ---------------------------------------------------------------------------
__global__ void out_proj_kernel(const bf16* __restrict__ ofin, const float* __restrict__ Wfin,
        const float* __restrict__ bfin, void* __restrict__ out, long obase, int cnt,
        const int* __restrict__ flag)
{
    const int id = blockIdx.x * 256 + threadIdx.x;
    if (id >= cnt * OUTD) return;
    const int i = id / OUTD, j = id % OUTD;
    const bf16* orow = ofin + (long)i * EE;
    float acc = bfin[j];
    for (int a = 0; a < EE; ++a)
        acc += __bfloat162float(orow[a]) * Wfin[a * OUTD + j];
    float r = acc > 0.f ? acc : expm1f(acc);
    if (*flag) ((bf16*)out)[obase + id] = __float2bfloat16(r);
    else       ((float*)out)[obase + id] = r;
}

// ---------------------------------------------------------------------------
extern "C" void kernel_launch(void* const* d_in, const int* in_sizes, int n_in,
                              void* d_out, int out_size, void* d_ws, size_t ws_size,
                              hipStream_t stream)
{
    const int* in_idx  = (const int*)d_in[1];
    const int* out_idx = (const int*)d_in[2];

    char* p = (char*)d_ws;
    auto alloc = [&](size_t bytes) { char* r = p; p += (bytes + 255) & ~(size_t)255; return r; };
    int*   flag      = (int*)alloc(256);
    // converted f32 inputs
    float* Xf        = (float*)alloc((size_t)NNODE * EE * 4);
    float* Wq_in_f   = (float*)alloc((size_t)EE * EE * 4);
    float* Wk_in_f   = (float*)alloc((size_t)EE * EE * 4);
    float* Wv_in_f   = (float*)alloc((size_t)EE * EE * 4);
    float* Wq_out_f  = (float*)alloc((size_t)EE * EE * 4);
    float* Wk_out_f  = (float*)alloc((size_t)EE * EE * 4);
    float* Wv_out_f  = (float*)alloc((size_t)EE * EE * 4);
    float* qkvw_in_f = (float*)alloc((size_t)3 * EE * EE * 4);
    float* qkvw_out_f= (float*)alloc((size_t)3 * EE * EE * 4);
    float* qkvw_fin_f= (float*)alloc((size_t)3 * EE * EE * 4);
    float* bcat      = (float*)alloc(PCOLS * 4);          // [in_qkv_b | out_qkv_b]
    float* qkvb_fin_f= (float*)alloc(3 * EE * 4);
    float* ow_in_f   = (float*)alloc((size_t)EE * EE * 4);
    float* ow_out_f  = (float*)alloc((size_t)EE * EE * 4);
    float* ow_fin_f  = (float*)alloc((size_t)EE * EE * 4);
    float* ob_in_f   = (float*)alloc(EE * 4);
    float* ob_out_f  = (float*)alloc(EE * 4);
    float* ob_fin_f  = (float*)alloc(EE * 4);
    float* W_f       = (float*)alloc((size_t)EE * OUTD * 4);
    // composed
    float* Acat   = (float*)alloc((size_t)320 * PCOLS * 4);
    float* Qc_in  = (float*)alloc((size_t)320 * 320 * 4);
    float* Kc_in  = (float*)alloc((size_t)320 * 320 * 4);
    float* Kc_out = (float*)alloc((size_t)320 * 320 * 4);
    float* bqc_in = (float*)alloc(320 * 4);
    float* bkc_in = (float*)alloc(320 * 4);
    float* bkc_out= (float*)alloc(320 * 4);
    float* M2     = (float*)alloc((size_t)320 * KF * 4);
    float* bT     = (float*)alloc(KF * 4);
    float* Vcat   = (float*)alloc((size_t)KF * 320 * 4);
    float* Wfin   = (float*)alloc((size_t)320 * OUTD * 4);
    float* bfin   = (float*)alloc(64 * 4);
    bf16*  P      = (bf16*)alloc((size_t)NNODE * PCOLS * 2);
    size_t fixed = (size_t)(p - (char*)d_ws);

    const size_t per_node = (size_t)32 * EE * 2 + (size_t)KF * 4 + (size_t)KF * 2 + (size_t)EE * 2;
    size_t avail = (ws_size > fixed + 65536) ? (ws_size - fixed - 65536) : 0;
    long chunk_l = (long)(avail / (per_node + 8));
    int chunk = (chunk_l > NNODE) ? NNODE : (chunk_l < 1 ? 1 : (int)chunk_l);
    bf16*  O_c    = (bf16*)alloc((size_t)chunk * 32 * EE * 2);
    float* T_c    = (float*)alloc((size_t)chunk * KF * 4);
    bf16*  G_c    = (bf16*)alloc((size_t)chunk * KF * 2);
    bf16*  ofin_c = (bf16*)alloc((size_t)chunk * EE * 2);

    dim3 blk(256);
    // ---- detect dtype + normalize all float inputs to f32 ----
    detect_dtype_kernel<<<1, blk, 0, stream>>>((const unsigned int*)d_in[0], flag);
    struct Cv { const void* src; float* dst; int n; };
    const Cv cvs[] = {
        { d_in[0],  Xf,         NNODE * EE },
        { d_in[3],  Wq_in_f,    EE * EE }, { d_in[4],  Wk_in_f,  EE * EE },
        { d_in[5],  Wv_in_f,    EE * EE },
        { d_in[6],  qkvw_in_f,  3 * EE * EE }, { d_in[7],  bcat,       3 * EE },
        { d_in[8],  ow_in_f,    EE * EE },     { d_in[9],  ob_in_f,    EE },
        { d_in[10], Wq_out_f,   EE * EE }, { d_in[11], Wk_out_f, EE * EE },
        { d_in[12], Wv_out_f,   EE * EE },
        { d_in[13], qkvw_out_f, 3 * EE * EE }, { d_in[14], bcat + 960, 3 * EE },
        { d_in[15], ow_out_f,   EE * EE },     { d_in[16], ob_out_f,   EE },
        { d_in[17], qkvw_fin_f, 3 * EE * EE }, { d_in[18], qkvb_fin_f, 3 * EE },
        { d_in[19], ow_fin_f,   EE * EE },     { d_in[20], ob_fin_f,   EE },
        { d_in[21], W_f,        EE * OUTD },
    };
    for (const Cv& c : cvs)
        convert_kernel<<<(c.n + 255) / 256, blk, 0, stream>>>(c.src, c.dst, c.n, flag);

    // ---- compose ----
    const float* Wg[6] = {Wq_in_f, Wk_in_f, Wv_in_f, Wq_out_f, Wk_out_f, Wv_out_f};
    for (int g = 0; g < 6; ++g) {
        const float* qkvw = (g < 3) ? qkvw_in_f : qkvw_out_f;
        int sel = g % 3;
        gemm_k<false, true, float, float, float><<<dim3(5, 5), blk, 0, stream>>>(
            Wg[g], EE, qkvw + (size_t)sel * 320 * EE, EE, nullptr,
            Acat + g * 320, PCOLS, 320, 320, 320);
    }
    gemm_k<true, true, float, float, float><<<dim3(5, 5), blk, 0, stream>>>(
        ow_in_f, EE, qkvw_fin_f, EE, nullptr, Qc_in, 320, 320, 320, 320);
    gemm_k<true, true, float, float, float><<<dim3(5, 5), blk, 0, stream>>>(
        ow_in_f, EE, qkvw_fin_f + (size_t)320 * EE, EE, nullptr, Kc_in, 320, 320, 320, 320);
    gemm_k<true, true, float, float, float><<<dim3(5, 5), blk, 0, stream>>>(
        ow_out_f, EE, qkvw_fin_f + (size_t)320 * EE, EE, nullptr, Kc_out, 320, 320, 320, 320);
    gemm_k<true, true, float, float, float><<<dim3(5, 5), blk, 0, stream>>>(
        ow_in_f, EE, qkvw_fin_f + (size_t)640 * EE, EE, nullptr, Vcat, 320, 320, 320, 320);
    gemm_k<true, true, float, float, float><<<dim3(5, 5), blk, 0, stream>>>(
        ow_out_f, EE, qkvw_fin_f + (size_t)640 * EE, EE, nullptr, Vcat + (size_t)320 * 320, 320, 320, 320, 320);
    compose_bias_kernel<<<5, 320, 0, stream>>>(ob_in_f, ob_out_f, qkvw_fin_f, qkvb_fin_f,
                                               bqc_in, bkc_in, bkc_out, Vcat);
    gemm_k<true, false, float, float, float><<<dim3(1, 5), blk, 0, stream>>>(
        ow_fin_f, EE, W_f, OUTD, nullptr, Wfin, OUTD, 320, OUTD, 320);
    compose_bfin<<<1, 64, 0, stream>>>(ob_fin_f, W_f, bfin);
    compose_M2_kernel<<<321, 704, 0, stream>>>(Qc_in, bqc_in, Kc_in, Kc_out, bkc_in, bkc_out, M2, bT);

    // ---- P = X @ Acat + bcat ----
    gemm_k<false, false, float, float, bf16><<<dim3(PCOLS / 64, (NNODE + 63) / 64), blk, 0, stream>>>(
        Xf, EE, Acat, PCOLS, bcat, P, PCOLS, NNODE, PCOLS, 320);

    // ---- per-node pipeline (chunked) ----
    for (int base = 0; base < NNODE; base += chunk) {
        int cnt = (NNODE - base < chunk) ? (NNODE - base) : chunk;
        attn1_kernel<<<2 * cnt, blk, 0, stream>>>(P, in_idx, out_idx, O_c, base, cnt);
        gemm_k<false, false, bf16, float, float><<<dim3((KF + 63) / 64, (cnt + 63) / 64), blk, 0, stream>>>(
            O_c, 32 * EE, M2, KF, bT, T_c, KF, cnt, KF, 320);
        final_attn_kernel<<<cnt, blk, 0, stream>>>(O_c, T_c, G_c);
        gemm_k<false, false, bf16, float, bf16><<<dim3(EE / 64, (cnt + 63) / 64), blk, 0, stream>>>(
            G_c, KF, Vcat, 320, nullptr, ofin_c, 320, cnt, 320, KF);
        out_proj_kernel<<<(cnt * OUTD + 255) / 256, blk, 0, stream>>>(
            ofin_c, Wfin, bfin, d_out, (long)base * OUTD, cnt, flag);
    }
}

// Round 3
// 1371.411 us; speedup vs baseline: 2.0352x; 2.0352x over previous
//
#include <hip/hip_runtime.h>
#include <hip/hip_bf16.h>

typedef __hip_bfloat16 bf16;
typedef __bf16 nbf;
typedef nbf bf16x8 __attribute__((ext_vector_type(8)));
typedef float f32x4 __attribute__((ext_vector_type(4)));

#define NNODE 10000
#define DDEG  15
#define EE    320
#define LL    16
#define NH    5
#define HD    64
#define OUTD  30
#define PCOLS 1920   // 6*E : [Qin|Kin|Vin|Qout|Kout|Vout]
#define KF    642    // 2*E + 2 (alpha columns)
#define GST   648    // padded row stride for G (16B-aligned bf16 rows)

// ---------------------------------------------------------------------------
// dtype detection: bf16 data -> low-16 exponent field clustered in [100,140]
// ---------------------------------------------------------------------------
__global__ void detect_dtype_kernel(const unsigned int* __restrict__ X, int* __restrict__ flag)
{
    __shared__ int cnt;
    if (threadIdx.x == 0) cnt = 0;
    __syncthreads();
    int local = 0;
    for (int i = threadIdx.x; i < 1024; i += 256) {
        unsigned int lo = X[i] & 0xFFFFu;
        int e = (int)((lo >> 7) & 0xFFu);
        if (e >= 100 && e <= 140) local++;
    }
    atomicAdd(&cnt, local);
    __syncthreads();
    if (threadIdx.x == 0) *flag = (cnt > 512) ? 1 : 0;
}

__global__ void convert_kernel(const void* __restrict__ src, float* __restrict__ dst,
                               int n, const int* __restrict__ flag)
{
    int i = blockIdx.x * 256 + threadIdx.x;
    if (i >= n) return;
    if (*flag) dst[i] = __bfloat162float(((const bf16*)src)[i]);
    else       dst[i] = ((const float*)src)[i];
}

__global__ void convert_bf_kernel(const void* __restrict__ src, nbf* __restrict__ dst,
                                  int n, const int* __restrict__ flag)
{
    int i = blockIdx.x * 256 + threadIdx.x;
    if (i >= n) return;
    if (*flag) dst[i] = ((const nbf*)src)[i];
    else       dst[i] = (nbf)(((const float*)src)[i]);
}

__device__ __forceinline__ float cvt(float x) { return x; }
__device__ __forceinline__ void stor(float* p, float v) { *p = v; }
__device__ __forceinline__ void stor(bf16* p, float v) { *p = __float2bfloat16(v); }

// ---------------------------------------------------------------------------
// VALU 64x64 GEMM for the tiny compose ops (f32 inputs).
// BT: B passed as [N,K] row-major (i.e. multiplies by B^T)
// ---------------------------------------------------------------------------
template<bool AT, bool BT, typename OT>
__global__ __launch_bounds__(256) void gemm_k(const float* __restrict__ A, int lda,
                       const float* __restrict__ B, int ldb,
                       const float* __restrict__ bias,
                       OT* __restrict__ C, int ldc, int M, int Nn, int K)
{
    __shared__ float As[16][65];
    __shared__ float Bs[16][65];
    const int tid = threadIdx.x;
    const int tx = tid & 15, ty = tid >> 4;
    const int n0 = blockIdx.x * 64, m0 = blockIdx.y * 64;
    float acc[4][4] = {};
    for (int k0 = 0; k0 < K; k0 += 16) {
        if constexpr (AT) {
            for (int i = tid; i < 1024; i += 256) {
                int kk = i >> 6, r = i & 63;
                int gm = m0 + r, gk = k0 + kk;
                As[kk][r] = (gm < M && gk < K) ? A[(long)gk * lda + gm] : 0.f;
            }
        } else {
            for (int i = tid; i < 1024; i += 256) {
                int r = i >> 4, kk = i & 15;
                int gm = m0 + r, gk = k0 + kk;
                As[kk][r] = (gm < M && gk < K) ? A[(long)gm * lda + gk] : 0.f;
            }
        }
        if constexpr (BT) {
            for (int i = tid; i < 1024; i += 256) {
                int r = i >> 4, kk = i & 15;
                int gn = n0 + r, gk = k0 + kk;
                Bs[kk][r] = (gn < Nn && gk < K) ? B[(long)gn * ldb + gk] : 0.f;
            }
        } else {
            for (int i = tid; i < 1024; i += 256) {
                int kk = i >> 6, c = i & 63;
                int gk = k0 + kk, gn = n0 + c;
                Bs[kk][c] = (gk < K && gn < Nn) ? B[(long)gk * ldb + gn] : 0.f;
            }
        }
        __syncthreads();
        #pragma unroll
        for (int kk = 0; kk < 16; ++kk) {
            float ra[4], rb[4];
            #pragma unroll
            for (int a = 0; a < 4; ++a) ra[a] = As[kk][ty * 4 + a];
            #pragma unroll
            for (int b = 0; b < 4; ++b) rb[b] = Bs[kk][tx * 4 + b];
            #pragma unroll
            for (int a = 0; a < 4; ++a)
                #pragma unroll
                for (int b = 0; b < 4; ++b)
                    acc[a][b] += ra[a] * rb[b];
        }
        __syncthreads();
    }
    #pragma unroll
    for (int a = 0; a < 4; ++a) {
        int gm = m0 + ty * 4 + a;
        if (gm >= M) continue;
        #pragma unroll
        for (int b = 0; b < 4; ++b) {
            int gn = n0 + tx * 4 + b;
            if (gn >= Nn) continue;
            float v = acc[a][b] + (bias ? bias[gn] : 0.f);
            stor(&C[(long)gm * ldc + gn], v);
        }
    }
}

// ---------------------------------------------------------------------------
// MFMA bf16 GEMM: C[M,N] = A[M,K] @ Bt[N,K]^T + bias. 128x128 tile, BK=32.
// 4 waves; wave computes 64x64 via 4x4 grid of 16x16x32 MFMA tiles.
// A-frag: A[m=lane&15][k=(lane>>4)*8+j]; B-frag: Bt[n=lane&15][k=...];
// C/D: col=lane&15, row=(lane>>4)*4+reg  [verified m89/m91]
// ---------------------------------------------------------------------------
template<typename OT>
__global__ __launch_bounds__(256) void gemm_mfma(const nbf* __restrict__ A, int lda,
        const nbf* __restrict__ Bt, int ldb, const float* __restrict__ bias,
        OT* __restrict__ C, int ldc, int M, int Nn, int K)
{
    __shared__ __align__(16) nbf As[128][40];
    __shared__ __align__(16) nbf Bs[128][40];
    const int tid = threadIdx.x;
    const int lane = tid & 63, wave = tid >> 6;
    const int wr = (wave >> 1) * 64, wc = (wave & 1) * 64;
    const int m0 = blockIdx.y * 128, n0 = blockIdx.x * 128;
    const int lr = lane & 15, lq = lane >> 4;
    f32x4 acc[4][4];
    #pragma unroll
    for (int i = 0; i < 4; ++i)
        #pragma unroll
        for (int j = 0; j < 4; ++j) { acc[i][j][0]=0.f; acc[i][j][1]=0.f; acc[i][j][2]=0.f; acc[i][j][3]=0.f; }

    for (int k0 = 0; k0 < K; k0 += 32) {
        #pragma unroll
        for (int v = tid; v < 512; v += 256) {
            const int row = v >> 2, cv = (v & 3) << 3;
            const int gk = k0 + cv;
            // A tile
            {
                const int gm = m0 + row;
                bf16x8 val;
                if (gm < M && gk + 8 <= K) {
                    val = *(const bf16x8*)(A + (long)gm * lda + gk);
                } else {
                    union { bf16x8 v8; nbf e[8]; } u;
                    #pragma unroll
                    for (int j = 0; j < 8; ++j) {
                        float x = (gm < M && gk + j < K) ? (float)A[(long)gm * lda + gk + j] : 0.f;
                        u.e[j] = (nbf)x;
                    }
                    val = u.v8;
                }
                *(bf16x8*)&As[row][cv] = val;
            }
            // B tile
            {
                const int gn = n0 + row;
                bf16x8 val;
                if (gn < Nn && gk + 8 <= K) {
                    val = *(const bf16x8*)(Bt + (long)gn * ldb + gk);
                } else {
                    union { bf16x8 v8; nbf e[8]; } u;
                    #pragma unroll
                    for (int j = 0; j < 8; ++j) {
                        float x = (gn < Nn && gk + j < K) ? (float)Bt[(long)gn * ldb + gk + j] : 0.f;
                        u.e[j] = (nbf)x;
                    }
                    val = u.v8;
                }
                *(bf16x8*)&Bs[row][cv] = val;
            }
        }
        __syncthreads();
        bf16x8 af[4], bfv[4];
        #pragma unroll
        for (int i = 0; i < 4; ++i) af[i] = *(const bf16x8*)&As[wr + i * 16 + lr][lq * 8];
        #pragma unroll
        for (int j = 0; j < 4; ++j) bfv[j] = *(const bf16x8*)&Bs[wc + j * 16 + lr][lq * 8];
        #pragma unroll
        for (int i = 0; i < 4; ++i)
            #pragma unroll
            for (int j = 0; j < 4; ++j)
                acc[i][j] = __builtin_amdgcn_mfma_f32_16x16x32_bf16(af[i], bfv[j], acc[i][j], 0, 0, 0);
        __syncthreads();
    }
    #pragma unroll
    for (int i = 0; i < 4; ++i) {
        #pragma unroll
        for (int j = 0; j < 4; ++j) {
            const int gn = n0 + wc + j * 16 + lr;
            if (gn >= Nn) continue;
            const float bv = bias ? bias[gn] : 0.f;
            #pragma unroll
            for (int r = 0; r < 4; ++r) {
                const int gm = m0 + wr + i * 16 + lq * 4 + r;
                if (gm < M) stor(&C[(long)gm * ldc + gn], acc[i][j][r] + bv);
            }
        }
    }
}

// ---------------------------------------------------------------------------
// which: 0->bqc_in  1->Kcat row640 (bkc_in)  2->Kcat row641 (bkc_out)
//        3->VcatT col640 (bvc_in, bf16)      4->VcatT col641 (bvc_out, bf16)
// ---------------------------------------------------------------------------
__global__ __launch_bounds__(320) void compose_bias_kernel(
        const float* __restrict__ in_o_b, const float* __restrict__ out_o_b,
        const float* __restrict__ fin_qkv_w, const float* __restrict__ fin_qkv_b,
        float* __restrict__ bqc_in, float* __restrict__ Kcat, nbf* __restrict__ VcatT)
{
    const int which = blockIdx.x;
    const int b = threadIdx.x;
    const float* ob = (which == 2 || which == 4) ? out_o_b : in_o_b;
    const int off = (which == 0) ? 0 : (which <= 2) ? 320 : 640;
    float acc = fin_qkv_b[off + b];
    const float* wr = fin_qkv_w + (long)(off + b) * EE;
    for (int e = 0; e < EE; ++e) acc += ob[e] * wr[e];
    if (which == 0)      bqc_in[b] = acc;
    else if (which == 1) Kcat[(long)640 * EE + b] = acc;
    else if (which == 2) Kcat[(long)641 * EE + b] = acc;
    else if (which == 3) VcatT[(long)b * GST + 640] = (nbf)acc;
    else                 VcatT[(long)b * GST + 641] = (nbf)acc;
}

__global__ void compose_bfin(const float* __restrict__ fin_o_b, const float* __restrict__ W,
                             float* __restrict__ bfin)
{
    int j = threadIdx.x;
    if (j >= OUTD) return;
    float acc = 0.f;
    for (int e = 0; e < EE; ++e) acc += fin_o_b[e] * W[e * OUTD + j];
    bfin[j] = acc;
}

__global__ void compose_bT(const float* __restrict__ bqc, const float* __restrict__ Kcat,
                           float* __restrict__ bT)
{
    int c = blockIdx.x * 256 + threadIdx.x;
    if (c >= KF) return;
    const float* kr = Kcat + (long)c * EE;
    float acc = 0.f;
    for (int b = 0; b < EE; ++b) acc += bqc[b] * kr[b];
    bT[c] = acc;
}

// ---------------------------------------------------------------------------
// Layer-1 attention: one block per (node, dir). bf16 LDS, vec8 everywhere.
// ---------------------------------------------------------------------------
__global__ __launch_bounds__(256) void attn1_kernel(const nbf* __restrict__ P,
                const int* __restrict__ in_idx, const int* __restrict__ out_idx,
                nbf* __restrict__ O, int node_base)
{
    const int bx = blockIdx.x;
    const int lnode = bx >> 1, dir = bx & 1;
    const int node = node_base + lnode;
    const int tid = threadIdx.x;
    __shared__ __align__(16) nbf s[LL][968];     // [Q(0:320)|K(320:640)|V(640:960)] + pad
    __shared__ float a_s[NH][LL][LL];
    __shared__ int srcs[LL];
    if (tid == 0) srcs[0] = node;
    else if (tid < 16) {
        const int* idx = dir ? out_idx : in_idx;
        srcs[tid] = idx[node * DDEG + tid - 1];
    }
    __syncthreads();
    const long coloff = (long)dir * 960;
    for (int v = tid; v < 16 * 120; v += 256) {
        const int row = v / 120, cv = (v % 120) * 8;
        *(bf16x8*)&s[row][cv] = *(const bf16x8*)(P + (long)srcs[row] * PCOLS + coloff + cv);
    }
    __syncthreads();
    {
        const int l = tid >> 4, m = tid & 15;
        #pragma unroll
        for (int h = 0; h < NH; ++h) {
            float p = 0.f;
            #pragma unroll
            for (int jc = 0; jc < 8; ++jc) {
                bf16x8 qv = *(const bf16x8*)&s[l][h * 64 + jc * 8];
                bf16x8 kv = *(const bf16x8*)&s[m][320 + h * 64 + jc * 8];
                #pragma unroll
                for (int j = 0; j < 8; ++j) p += (float)qv[j] * (float)kv[j];
            }
            a_s[h][l][m] = p * 0.125f;   // 1/sqrt(64)
        }
    }
    __syncthreads();
    if (tid < NH * LL) {
        const int h = tid >> 4, l = tid & 15;
        float mx = -1e30f;
        for (int m = 0; m < LL; ++m) mx = fmaxf(mx, a_s[h][l][m]);
        float e[LL], sum = 0.f;
        for (int m = 0; m < LL; ++m) { e[m] = __expf(a_s[h][l][m] - mx); sum += e[m]; }
        float inv = 1.f / sum;
        for (int m = 0; m < LL; ++m) a_s[h][l][m] = e[m] * inv;
    }
    __syncthreads();
    nbf* orow = O + (long)lnode * (32 * EE) + dir * (16 * EE);
    for (int v = tid; v < 16 * 40; v += 256) {
        const int l = v / 40, cv = (v % 40) * 8;
        const int h = cv >> 6;
        float av[8] = {0.f,0.f,0.f,0.f,0.f,0.f,0.f,0.f};
        #pragma unroll
        for (int m = 0; m < LL; ++m) {
            const float a = a_s[h][l][m];
            bf16x8 vv = *(const bf16x8*)&s[m][640 + cv];
            #pragma unroll
            for (int j = 0; j < 8; ++j) av[j] += a * (float)vv[j];
        }
        union { bf16x8 v8; nbf e[8]; } u;
        #pragma unroll
        for (int j = 0; j < 8; ++j) u.e[j] = (nbf)av[j];
        *(bf16x8*)(orow + l * EE + cv) = u.v8;
    }
}

// ---------------------------------------------------------------------------
// Final attention: one block per node. G rows padded to GST for aligned vec8.
// ---------------------------------------------------------------------------
__global__ __launch_bounds__(256) void final_attn_kernel(const nbf* __restrict__ O,
                const float* __restrict__ T, nbf* __restrict__ G)
{
    const int i = blockIdx.x;
    const int tid = threadIdx.x;
    __shared__ __align__(16) nbf o_s[32][328];
    __shared__ float t_s[644];
    __shared__ float a_lds[32];
    const nbf* orow = O + (long)i * (32 * EE);
    for (int v = tid; v < 32 * 40; v += 256) {
        const int row = v / 40, cv = (v % 40) * 8;
        *(bf16x8*)&o_s[row][cv] = *(const bf16x8*)(orow + row * EE + cv);
    }
    for (int c = tid; c < KF; c += 256) t_s[c] = T[(long)i * KF + c];
    __syncthreads();
    {
        const int m = tid >> 3, sub = tid & 7;
        const int hoff = (m < 16) ? 0 : 320;
        float p = 0.f;
        #pragma unroll
        for (int jc = 0; jc < 5; ++jc) {
            const int e0 = (jc * 8 + sub) * 8;
            bf16x8 ov = *(const bf16x8*)&o_s[m][e0];
            #pragma unroll
            for (int j = 0; j < 8; ++j) p += (float)ov[j] * t_s[hoff + e0 + j];
        }
        p += __shfl_down(p, 4, 8);
        p += __shfl_down(p, 2, 8);
        p += __shfl_down(p, 1, 8);
        if (sub == 0) a_lds[m] = (p + t_s[(m < 16) ? 640 : 641]) * 0.05590169943749474f;
    }
    __syncthreads();
    if (tid < 32) {
        float sv = a_lds[tid];
        float mx = sv;
        for (int o = 16; o > 0; o >>= 1) mx = fmaxf(mx, __shfl_xor(mx, o, 32));
        float e = __expf(sv - mx);
        float sm = e;
        for (int o = 16; o > 0; o >>= 1) sm += __shfl_xor(sm, o, 32);
        a_lds[tid] = e / sm;
    }
    __syncthreads();
    nbf* grow = G + (long)i * GST;
    if (tid < 2) {
        float sm = 0.f;
        for (int m = tid * 16; m < tid * 16 + 16; ++m) sm += a_lds[m];
        grow[640 + tid] = (nbf)sm;
    }
    for (int v = tid; v < 80; v += 256) {
        const int half = v / 40, cv = (v % 40) * 8;
        float av[8] = {0.f,0.f,0.f,0.f,0.f,0.f,0.f,0.f};
        #pragma unroll
        for (int m = 0; m < 16; ++m) {
            const float a = a_lds[half * 16 + m];
            bf16x8 ov = *(const bf16x8*)&o_s[half * 16 + m][cv];
            #pragma unroll
            for (int j = 0; j < 8; ++j) av[j] += a * (float)ov[j];
        }
        union { bf16x8 v8; nbf e[8]; } u;
        #pragma unroll
        for (int j = 0; j < 8; ++j) u.e[j] = (nbf)av[j];
        *(bf16x8*)(grow + half * 320 + cv) = u.v8;
    }
}

// ---------------------------------------------------------------------------
// out[i,j] = elu( ofin[i,:] @ Wfin[:,j] + bfin[j] ); Wfin cached in LDS
// ---------------------------------------------------------------------------
__global__ __launch_bounds__(256) void out_proj_kernel(const nbf* __restrict__ ofin,
        const float* __restrict__ Wfin, const float* __restrict__ bfin,
        void* __restrict__ out, long obase, int total, const int* __restrict__ flag)
{
    __shared__ float Wf[320][OUTD];
    __shared__ float bf_s[OUTD];
    for (int v = threadIdx.x; v < 320 * OUTD; v += 256) Wf[v / OUTD][v % OUTD] = Wfin[v];
    if (threadIdx.x < OUTD) bf_s[threadIdx.x] = bfin[threadIdx.x];
    __syncthreads();
    const int id = blockIdx.x * 256 + threadIdx.x;
    if (id >= total) return;
    const int i = id / OUTD, j = id % OUTD;
    const bf16x8* row = (const bf16x8*)(ofin + (long)i * EE);
    float acc = bf_s[j];
    #pragma unroll
    for (int cv = 0; cv < 40; ++cv) {
        bf16x8 ov = row[cv];
        #pragma unroll
        for (int jj = 0; jj < 8; ++jj) acc += (float)ov[jj] * Wf[cv * 8 + jj][j];
    }
    float r = acc > 0.f ? acc : expm1f(acc);
    if (*flag) ((bf16*)out)[obase + id] = __float2bfloat16(r);
    else       ((float*)out)[obase + id] = r;
}

// ---------------------------------------------------------------------------
extern "C" void kernel_launch(void* const* d_in, const int* in_sizes, int n_in,
                              void* d_out, int out_size, void* d_ws, size_t ws_size,
                              hipStream_t stream)
{
    const int* in_idx  = (const int*)d_in[1];
    const int* out_idx = (const int*)d_in[2];

    char* p = (char*)d_ws;
    auto alloc = [&](size_t bytes) { char* r = p; p += (bytes + 255) & ~(size_t)255; return r; };
    int*   flag      = (int*)alloc(256);
    nbf*   X_bf      = (nbf*)alloc((size_t)NNODE * EE * 2);
    // f32 weight copies
    float* Wq_in_f   = (float*)alloc((size_t)EE * EE * 4);
    float* Wk_in_f   = (float*)alloc((size_t)EE * EE * 4);
    float* Wv_in_f   = (float*)alloc((size_t)EE * EE * 4);
    float* Wq_out_f  = (float*)alloc((size_t)EE * EE * 4);
    float* Wk_out_f  = (float*)alloc((size_t)EE * EE * 4);
    float* Wv_out_f  = (float*)alloc((size_t)EE * EE * 4);
    float* qkvw_in_f = (float*)alloc((size_t)3 * EE * EE * 4);
    float* qkvw_out_f= (float*)alloc((size_t)3 * EE * EE * 4);
    float* qkvw_fin_f= (float*)alloc((size_t)3 * EE * EE * 4);
    float* bcat      = (float*)alloc(PCOLS * 4);
    float* qkvb_fin_f= (float*)alloc(3 * EE * 4);
    float* ow_in_f   = (float*)alloc((size_t)EE * EE * 4);
    float* ow_out_f  = (float*)alloc((size_t)EE * EE * 4);
    float* ow_fin_f  = (float*)alloc((size_t)EE * EE * 4);
    float* ob_in_f   = (float*)alloc(EE * 4);
    float* ob_out_f  = (float*)alloc(EE * 4);
    float* ob_fin_f  = (float*)alloc(EE * 4);
    float* W_f       = (float*)alloc((size_t)EE * OUTD * 4);
    // composed (transposed, bf16 where MFMA consumes them)
    nbf*   AcatT  = (nbf*)alloc((size_t)PCOLS * EE * 2);      // [1920][320]
    float* Qc_in  = (float*)alloc((size_t)EE * EE * 4);
    float* Kcat   = (float*)alloc((size_t)KF * EE * 4);       // [642][320]
    float* bqc_in = (float*)alloc(EE * 4);
    nbf*   M2T    = (nbf*)alloc((size_t)KF * EE * 2);         // [642][320]
    float* bT     = (float*)alloc(KF * 4);
    nbf*   VcatT  = (nbf*)alloc((size_t)EE * GST * 2);        // [320][648]
    float* Wfin   = (float*)alloc((size_t)EE * OUTD * 4);
    float* bfin   = (float*)alloc(64 * 4);
    nbf*   P      = (nbf*)alloc((size_t)NNODE * PCOLS * 2);
    size_t fixed = (size_t)(p - (char*)d_ws);

    const size_t per_node = (size_t)32 * EE * 2 + (size_t)KF * 4 + (size_t)GST * 2 + (size_t)EE * 2;
    size_t avail = (ws_size > fixed + 65536) ? (ws_size - fixed - 65536) : 0;
    long chunk_l = (long)(avail / (per_node + 8));
    int chunk = (chunk_l > NNODE) ? NNODE : (chunk_l < 1 ? 1 : (int)chunk_l);
    nbf*   O_c    = (nbf*)alloc((size_t)chunk * 32 * EE * 2);
    float* T_c    = (float*)alloc((size_t)chunk * KF * 4);
    nbf*   G_c    = (nbf*)alloc((size_t)chunk * GST * 2);
    nbf*   ofin_c = (nbf*)alloc((size_t)chunk * EE * 2);

    dim3 blk(256);
    // ---- detect dtype + normalize inputs ----
    detect_dtype_kernel<<<1, blk, 0, stream>>>((const unsigned int*)d_in[0], flag);
    convert_bf_kernel<<<(NNODE * EE + 255) / 256, blk, 0, stream>>>(d_in[0], X_bf, NNODE * EE, flag);
    struct Cv { const void* src; float* dst; int n; };
    const Cv cvs[] = {
        { d_in[3],  Wq_in_f,    EE * EE }, { d_in[4],  Wk_in_f,  EE * EE },
        { d_in[5],  Wv_in_f,    EE * EE },
        { d_in[6],  qkvw_in_f,  3 * EE * EE }, { d_in[7],  bcat,       3 * EE },
        { d_in[8],  ow_in_f,    EE * EE },     { d_in[9],  ob_in_f,    EE },
        { d_in[10], Wq_out_f,   EE * EE }, { d_in[11], Wk_out_f, EE * EE },
        { d_in[12], Wv_out_f,   EE * EE },
        { d_in[13], qkvw_out_f, 3 * EE * EE }, { d_in[14], bcat + 960, 3 * EE },
        { d_in[15], ow_out_f,   EE * EE },     { d_in[16], ob_out_f,   EE },
        { d_in[17], qkvw_fin_f, 3 * EE * EE }, { d_in[18], qkvb_fin_f, 3 * EE },
        { d_in[19], ow_fin_f,   EE * EE },     { d_in[20], ob_fin_f,   EE },
        { d_in[21], W_f,        EE * OUTD },
    };
    for (const Cv& c : cvs)
        convert_kernel<<<(c.n + 255) / 256, blk, 0, stream>>>(c.src, c.dst, c.n, flag);

    // ---- compose (directly in B^T layout) ----
    const float* Wg[6] = {Wq_in_f, Wk_in_f, Wv_in_f, Wq_out_f, Wk_out_f, Wv_out_f};
    for (int g = 0; g < 6; ++g) {
        const float* qkvw = (g < 3) ? qkvw_in_f : qkvw_out_f;
        int sel = g % 3;
        // AcatT rows [g*320, (g+1)*320) = qkvw_sel @ Wg^T
        gemm_k<false, true, bf16><<<dim3(5, 5), blk, 0, stream>>>(
            qkvw + (size_t)sel * EE * EE, EE, Wg[g], EE, nullptr,
            (bf16*)(AcatT + (size_t)g * EE * EE), EE, EE, EE, EE);
    }
    gemm_k<true, true, float><<<dim3(5, 5), blk, 0, stream>>>(
        ow_in_f, EE, qkvw_fin_f, EE, nullptr, Qc_in, EE, EE, EE, EE);
    gemm_k<true, true, float><<<dim3(5, 5), blk, 0, stream>>>(
        ow_in_f, EE, qkvw_fin_f + (size_t)320 * EE, EE, nullptr, Kcat, EE, EE, EE, EE);
    gemm_k<true, true, float><<<dim3(5, 5), blk, 0, stream>>>(
        ow_out_f, EE, qkvw_fin_f + (size_t)320 * EE, EE, nullptr, Kcat + (size_t)320 * EE, EE, EE, EE, EE);
    // VcatT cols [0,320) = wv_f @ ow_in ; cols [320,640) = wv_f @ ow_out
    gemm_k<false, false, bf16><<<dim3(5, 5), blk, 0, stream>>>(
        qkvw_fin_f + (size_t)640 * EE, EE, ow_in_f, EE, nullptr,
        (bf16*)VcatT, GST, EE, EE, EE);
    gemm_k<false, false, bf16><<<dim3(5, 5), blk, 0, stream>>>(
        qkvw_fin_f + (size_t)640 * EE, EE, ow_out_f, EE, nullptr,
        (bf16*)(VcatT + 320), GST, EE, EE, EE);
    compose_bias_kernel<<<5, 320, 0, stream>>>(ob_in_f, ob_out_f, qkvw_fin_f, qkvb_fin_f,
                                               bqc_in, Kcat, VcatT);
    // M2T[642][320] = Kcat @ Qc^T  (after compose_bias filled rows 640/641)
    gemm_k<false, true, bf16><<<dim3(5, 11), blk, 0, stream>>>(
        Kcat, EE, Qc_in, EE, nullptr, (bf16*)M2T, EE, KF, EE, EE);
    compose_bT<<<3, blk, 0, stream>>>(bqc_in, Kcat, bT);
    gemm_k<true, false, float><<<dim3(1, 5), blk, 0, stream>>>(
        ow_fin_f, EE, W_f, OUTD, nullptr, Wfin, OUTD, EE, OUTD, EE);
    compose_bfin<<<1, 64, 0, stream>>>(ob_fin_f, W_f, bfin);

    // ---- P = X @ Acat + bcat  (MFMA) ----
    gemm_mfma<bf16><<<dim3(PCOLS / 128, (NNODE + 127) / 128), blk, 0, stream>>>(
        X_bf, EE, AcatT, EE, bcat, (bf16*)P, PCOLS, NNODE, PCOLS, EE);

    // ---- per-node pipeline (chunked) ----
    for (int base = 0; base < NNODE; base += chunk) {
        int cnt = (NNODE - base < chunk) ? (NNODE - base) : chunk;
        attn1_kernel<<<2 * cnt, blk, 0, stream>>>(P, in_idx, out_idx, O_c, base);
        gemm_mfma<float><<<dim3((KF + 127) / 128, (cnt + 127) / 128), blk, 0, stream>>>(
            O_c, 32 * EE, M2T, EE, bT, T_c, KF, cnt, KF, EE);
        final_attn_kernel<<<cnt, blk, 0, stream>>>(O_c, T_c, G_c);
        gemm_mfma<bf16><<<dim3((EE + 127) / 128, (cnt + 127) / 128), blk, 0, stream>>>(
            G_c, GST, VcatT, GST, nullptr, (bf16*)ofin_c, EE, cnt, EE, KF);
        out_proj_kernel<<<(cnt * OUTD + 255) / 256, blk, 0, stream>>>(
            ofin_c, Wfin, bfin, d_out, (long)base * OUTD, cnt * OUTD, flag);
    }
}

// Round 4
// 747.506 us; speedup vs baseline: 3.7339x; 1.8346x over previous
//
#include <hip/hip_runtime.h>
#include <hip/hip_bf16.h>

typedef __hip_bfloat16 bf16;
typedef __bf16 nbf;
typedef nbf bf16x8 __attribute__((ext_vector_type(8)));
typedef float f32x4 __attribute__((ext_vector_type(4)));

#define NNODE 10000
#define DDEG  15
#define EE    320
#define LL    16
#define NH    5
#define HD    64
#define OUTD  30
#define PCOLS 1920   // 6*E : [Qin|Kin|Vin|Qout|Kout|Vout]
#define KF    642    // 2*E + 2 (alpha columns)
#define GST   648    // padded row stride for G (16B-aligned bf16 rows)

// ---------------------------------------------------------------------------
// dtype detection: bf16 data -> low-16 exponent field clustered in [100,140]
// ---------------------------------------------------------------------------
__global__ void detect_dtype_kernel(const unsigned int* __restrict__ X, int* __restrict__ flag)
{
    __shared__ int cnt;
    if (threadIdx.x == 0) cnt = 0;
    __syncthreads();
    int local = 0;
    for (int i = threadIdx.x; i < 1024; i += 256) {
        unsigned int lo = X[i] & 0xFFFFu;
        int e = (int)((lo >> 7) & 0xFFu);
        if (e >= 100 && e <= 140) local++;
    }
    atomicAdd(&cnt, local);
    __syncthreads();
    if (threadIdx.x == 0) *flag = (cnt > 512) ? 1 : 0;
}

__global__ void convert_bf_kernel(const void* __restrict__ src, nbf* __restrict__ dst,
                                  int n, const int* __restrict__ flag)
{
    int i = blockIdx.x * 256 + threadIdx.x;
    if (i >= n) return;
    if (*flag) dst[i] = ((const nbf*)src)[i];
    else       dst[i] = (nbf)(((const float*)src)[i]);
}

#define NSEG 18
struct ConvTab {
    const void* src[NSEG];
    void*       dst[NSEG];
    int         n[NSEG];
    int         tobf[NSEG];
};

__global__ void convert_batch_kernel(ConvTab t, const int* __restrict__ flag)
{
    const int seg = blockIdx.y;
    const int i = blockIdx.x * 256 + threadIdx.x;
    if (i >= t.n[seg]) return;
    float v = (*flag) ? (float)(((const nbf*)t.src[seg])[i]) : ((const float*)t.src[seg])[i];
    if (t.tobf[seg]) ((nbf*)t.dst[seg])[i] = (nbf)v;
    else             ((float*)t.dst[seg])[i] = v;
}

// 3 batched 320x320 transposes: dst[a][e] = src[e][a] (bf16 out)
__global__ __launch_bounds__(256) void transpose3_kernel(const void* s0, const void* s1,
        const void* s2, nbf* __restrict__ dstbase, const int* __restrict__ flag)
{
    const void* src = (blockIdx.z == 0) ? s0 : (blockIdx.z == 1) ? s1 : s2;
    nbf* dst = dstbase + (size_t)blockIdx.z * EE * EE;
    __shared__ nbf tile[32][33];
    const int bx = blockIdx.x * 32, by = blockIdx.y * 32;
    const int tx = threadIdx.x & 31, ty = threadIdx.x >> 5;
    const int f = *flag;
    #pragma unroll
    for (int i = 0; i < 4; ++i) {
        const int r = by + ty + i * 8;
        float v = f ? (float)(((const nbf*)src)[(long)r * EE + bx + tx])
                    : ((const float*)src)[(long)r * EE + bx + tx];
        tile[ty + i * 8][tx] = (nbf)v;
    }
    __syncthreads();
    #pragma unroll
    for (int i = 0; i < 4; ++i) {
        const int r = bx + ty + i * 8;
        dst[(long)r * EE + by + tx] = tile[tx][ty + i * 8];
    }
}

__device__ __forceinline__ void stor(float* p, float v) { *p = v; }
__device__ __forceinline__ void stor(bf16* p, float v) { *p = __float2bfloat16(v); }

// ---------------------------------------------------------------------------
// VALU 64x64 GEMM (kept only for the tiny Wfin compose; f32 in)
// ---------------------------------------------------------------------------
template<bool AT, bool BT, typename OT>
__global__ __launch_bounds__(256) void gemm_k(const float* __restrict__ A, int lda,
                       const float* __restrict__ B, int ldb,
                       const float* __restrict__ bias,
                       OT* __restrict__ C, int ldc, int M, int Nn, int K)
{
    __shared__ float As[16][65];
    __shared__ float Bs[16][65];
    const int tid = threadIdx.x;
    const int tx = tid & 15, ty = tid >> 4;
    const int n0 = blockIdx.x * 64, m0 = blockIdx.y * 64;
    float acc[4][4] = {};
    for (int k0 = 0; k0 < K; k0 += 16) {
        if constexpr (AT) {
            for (int i = tid; i < 1024; i += 256) {
                int kk = i >> 6, r = i & 63;
                int gm = m0 + r, gk = k0 + kk;
                As[kk][r] = (gm < M && gk < K) ? A[(long)gk * lda + gm] : 0.f;
            }
        } else {
            for (int i = tid; i < 1024; i += 256) {
                int r = i >> 4, kk = i & 15;
                int gm = m0 + r, gk = k0 + kk;
                As[kk][r] = (gm < M && gk < K) ? A[(long)gm * lda + gk] : 0.f;
            }
        }
        if constexpr (BT) {
            for (int i = tid; i < 1024; i += 256) {
                int r = i >> 4, kk = i & 15;
                int gn = n0 + r, gk = k0 + kk;
                Bs[kk][r] = (gn < Nn && gk < K) ? B[(long)gn * ldb + gk] : 0.f;
            }
        } else {
            for (int i = tid; i < 1024; i += 256) {
                int kk = i >> 6, c = i & 63;
                int gk = k0 + kk, gn = n0 + c;
                Bs[kk][c] = (gk < K && gn < Nn) ? B[(long)gk * ldb + gn] : 0.f;
            }
        }
        __syncthreads();
        #pragma unroll
        for (int kk = 0; kk < 16; ++kk) {
            float ra[4], rb[4];
            #pragma unroll
            for (int a = 0; a < 4; ++a) ra[a] = As[kk][ty * 4 + a];
            #pragma unroll
            for (int b = 0; b < 4; ++b) rb[b] = Bs[kk][tx * 4 + b];
            #pragma unroll
            for (int a = 0; a < 4; ++a)
                #pragma unroll
                for (int b = 0; b < 4; ++b)
                    acc[a][b] += ra[a] * rb[b];
        }
        __syncthreads();
    }
    #pragma unroll
    for (int a = 0; a < 4; ++a) {
        int gm = m0 + ty * 4 + a;
        if (gm >= M) continue;
        #pragma unroll
        for (int b = 0; b < 4; ++b) {
            int gn = n0 + tx * 4 + b;
            if (gn >= Nn) continue;
            float v = acc[a][b] + (bias ? bias[gn] : 0.f);
            stor(&C[(long)gm * ldc + gn], v);
        }
    }
}

// ---------------------------------------------------------------------------
// MFMA bf16 GEMM: C[M,N] = A[M,K] @ Bt[N,K]^T + bias. 128x128 tile, BK=32.
// z-batched via strideA/strideB/strideC (elements).
// ---------------------------------------------------------------------------
template<typename OT>
__global__ __launch_bounds__(256) void gemm_mfma(const nbf* __restrict__ A, int lda,
        const nbf* __restrict__ Bt, int ldb, const float* __restrict__ bias,
        OT* __restrict__ C, int ldc, int M, int Nn, int K,
        long strideA, long strideB, long strideC)
{
    A  += (long)blockIdx.z * strideA;
    Bt += (long)blockIdx.z * strideB;
    C  += (long)blockIdx.z * strideC;
    __shared__ __align__(16) nbf As[128][40];
    __shared__ __align__(16) nbf Bs[128][40];
    const int tid = threadIdx.x;
    const int lane = tid & 63, wave = tid >> 6;
    const int wr = (wave >> 1) * 64, wc = (wave & 1) * 64;
    const int m0 = blockIdx.y * 128, n0 = blockIdx.x * 128;
    const int lr = lane & 15, lq = lane >> 4;
    f32x4 acc[4][4];
    #pragma unroll
    for (int i = 0; i < 4; ++i)
        #pragma unroll
        for (int j = 0; j < 4; ++j) { acc[i][j][0]=0.f; acc[i][j][1]=0.f; acc[i][j][2]=0.f; acc[i][j][3]=0.f; }

    for (int k0 = 0; k0 < K; k0 += 32) {
        #pragma unroll
        for (int v = tid; v < 512; v += 256) {
            const int row = v >> 2, cv = (v & 3) << 3;
            const int gk = k0 + cv;
            {
                const int gm = m0 + row;
                bf16x8 val;
                if (gm < M && gk + 8 <= K) {
                    val = *(const bf16x8*)(A + (long)gm * lda + gk);
                } else {
                    union { bf16x8 v8; nbf e[8]; } u;
                    #pragma unroll
                    for (int j = 0; j < 8; ++j) {
                        float x = (gm < M && gk + j < K) ? (float)A[(long)gm * lda + gk + j] : 0.f;
                        u.e[j] = (nbf)x;
                    }
                    val = u.v8;
                }
                *(bf16x8*)&As[row][cv] = val;
            }
            {
                const int gn = n0 + row;
                bf16x8 val;
                if (gn < Nn && gk + 8 <= K) {
                    val = *(const bf16x8*)(Bt + (long)gn * ldb + gk);
                } else {
                    union { bf16x8 v8; nbf e[8]; } u;
                    #pragma unroll
                    for (int j = 0; j < 8; ++j) {
                        float x = (gn < Nn && gk + j < K) ? (float)Bt[(long)gn * ldb + gk + j] : 0.f;
                        u.e[j] = (nbf)x;
                    }
                    val = u.v8;
                }
                *(bf16x8*)&Bs[row][cv] = val;
            }
        }
        __syncthreads();
        bf16x8 af[4], bfv[4];
        #pragma unroll
        for (int i = 0; i < 4; ++i) af[i] = *(const bf16x8*)&As[wr + i * 16 + lr][lq * 8];
        #pragma unroll
        for (int j = 0; j < 4; ++j) bfv[j] = *(const bf16x8*)&Bs[wc + j * 16 + lr][lq * 8];
        #pragma unroll
        for (int i = 0; i < 4; ++i)
            #pragma unroll
            for (int j = 0; j < 4; ++j)
                acc[i][j] = __builtin_amdgcn_mfma_f32_16x16x32_bf16(af[i], bfv[j], acc[i][j], 0, 0, 0);
        __syncthreads();
    }
    #pragma unroll
    for (int i = 0; i < 4; ++i) {
        #pragma unroll
        for (int j = 0; j < 4; ++j) {
            const int gn = n0 + wc + j * 16 + lr;
            if (gn >= Nn) continue;
            const float bv = bias ? bias[gn] : 0.f;
            #pragma unroll
            for (int r = 0; r < 4; ++r) {
                const int gm = m0 + wr + i * 16 + lq * 4 + r;
                if (gm < M) stor(&C[(long)gm * ldc + gn], acc[i][j][r] + bv);
            }
        }
    }
}

// ---------------------------------------------------------------------------
// which: 0->bqc_in  1->Kcat row640 (bkc_in)  2->Kcat row641 (bkc_out)
//        3->VcatT col640 (bvc_in)            4->VcatT col641 (bvc_out)
// ---------------------------------------------------------------------------
__global__ __launch_bounds__(320) void compose_bias_kernel(
        const float* __restrict__ in_o_b, const float* __restrict__ out_o_b,
        const float* __restrict__ fin_qkv_w, const float* __restrict__ fin_qkv_b,
        float* __restrict__ bqc_in, nbf* __restrict__ Kcat, nbf* __restrict__ VcatT)
{
    const int which = blockIdx.x;
    const int b = threadIdx.x;
    const float* ob = (which == 2 || which == 4) ? out_o_b : in_o_b;
    const int off = (which == 0) ? 0 : (which <= 2) ? 320 : 640;
    float acc = fin_qkv_b[off + b];
    const float* wr = fin_qkv_w + (long)(off + b) * EE;
    for (int e = 0; e < EE; ++e) acc += ob[e] * wr[e];
    if (which == 0)      bqc_in[b] = acc;
    else if (which == 1) Kcat[(long)640 * EE + b] = (nbf)acc;
    else if (which == 2) Kcat[(long)641 * EE + b] = (nbf)acc;
    else if (which == 3) VcatT[(long)b * GST + 640] = (nbf)acc;
    else                 VcatT[(long)b * GST + 641] = (nbf)acc;
}

__global__ void compose_bfin(const float* __restrict__ fin_o_b, const float* __restrict__ W,
                             float* __restrict__ bfin)
{
    int j = threadIdx.x;
    if (j >= OUTD) return;
    float acc = 0.f;
    for (int e = 0; e < EE; ++e) acc += fin_o_b[e] * W[e * OUTD + j];
    bfin[j] = acc;
}

__global__ void compose_bT(const float* __restrict__ bqc, const nbf* __restrict__ Kcat,
                           float* __restrict__ bT)
{
    int c = blockIdx.x * 256 + threadIdx.x;
    if (c >= KF) return;
    const nbf* kr = Kcat + (long)c * EE;
    float acc = 0.f;
    for (int b = 0; b < EE; ++b) acc += bqc[b] * (float)kr[b];
    bT[c] = acc;
}

// ---------------------------------------------------------------------------
// Layer-1 attention, MFMA version. Block = 320 threads = 5 waves (1 per head).
// QK^T: 2x mfma_16x16x32; softmax in-register (reduce over lanes 0..15);
// AV as O^T = V^T @ P^T so output lands 4-consecutive-e per lane.
// ---------------------------------------------------------------------------
__global__ __launch_bounds__(320) void attn1_kernel(const nbf* __restrict__ P,
                const int* __restrict__ in_idx, const int* __restrict__ out_idx,
                nbf* __restrict__ O, int node_base)
{
    const int bx = blockIdx.x;
    const int lnode = bx >> 1, dir = bx & 1;
    const int node = node_base + lnode;
    const int tid = threadIdx.x;
    const int lane = tid & 63, wave = tid >> 6;      // wave == head
    __shared__ __align__(16) nbf qk_s[16][648];      // [Q 0:320 | K 320:640 | pad]
    __shared__ __align__(16) nbf v_s[16][328];
    __shared__ __align__(16) nbf p_s[NH][16][16];
    __shared__ int srcs[16];
    if (tid < 16) {
        const int* idx = dir ? out_idx : in_idx;
        srcs[tid] = (tid == 0) ? node : idx[node * DDEG + tid - 1];
    }
    __syncthreads();
    const long coloff = (long)dir * 960;
    for (int v = tid; v < 16 * 120; v += 320) {
        const int row = v / 120, c8 = (v % 120) * 8;
        bf16x8 val = *(const bf16x8*)(P + (long)srcs[row] * PCOLS + coloff + c8);
        if (c8 < 640) *(bf16x8*)&qk_s[row][c8] = val;
        else          *(bf16x8*)&v_s[row][c8 - 640] = val;
    }
    __syncthreads();
    const int lr = lane & 15, lq = lane >> 4;
    // ---- QK^T (head = wave), K-dim 64 = 2 MFMA steps ----
    f32x4 sc = {0.f, 0.f, 0.f, 0.f};
    #pragma unroll
    for (int c = 0; c < 2; ++c) {
        bf16x8 aq = *(const bf16x8*)&qk_s[lr][wave * 64 + c * 32 + lq * 8];
        bf16x8 bk = *(const bf16x8*)&qk_s[lr][320 + wave * 64 + c * 32 + lq * 8];
        sc = __builtin_amdgcn_mfma_f32_16x16x32_bf16(aq, bk, sc, 0, 0, 0);
    }
    // ---- softmax over key index m (= lane&15, across 16-lane groups) ----
    float pr[4], mx[4], sm[4];
    #pragma unroll
    for (int r = 0; r < 4; ++r) { pr[r] = sc[r] * 0.125f; mx[r] = pr[r]; }
    #pragma unroll
    for (int msk = 8; msk >= 1; msk >>= 1)
        #pragma unroll
        for (int r = 0; r < 4; ++r) mx[r] = fmaxf(mx[r], __shfl_xor(mx[r], msk));
    #pragma unroll
    for (int r = 0; r < 4; ++r) { pr[r] = __expf(pr[r] - mx[r]); sm[r] = pr[r]; }
    #pragma unroll
    for (int msk = 8; msk >= 1; msk >>= 1)
        #pragma unroll
        for (int r = 0; r < 4; ++r) sm[r] += __shfl_xor(sm[r], msk);
    // P[l=lq*4+r][m=lr] -> LDS (bf16). Per-wave private: no block barrier needed.
    #pragma unroll
    for (int r = 0; r < 4; ++r) p_s[wave][lq * 4 + r][lr] = (nbf)(pr[r] / sm[r]);
    // B-frag = P^T: lane reads p_s[wave][n=lr][k=lq*8+j], zeros for k>=16
    union { bf16x8 v8; nbf e[8]; } pf;
    #pragma unroll
    for (int j = 0; j < 8; ++j) pf.e[j] = (nbf)0.f;
    if (lq < 2) pf.v8 = *(const bf16x8*)&p_s[wave][lr][lq * 8];
    // ---- O^T[e][l] = sum_m V[m][e] * P[l][m], e in head's 64-col slab ----
    nbf* orow = O + (long)lnode * (32 * EE) + dir * (16 * EE);
    #pragma unroll
    for (int t = 0; t < 4; ++t) {
        const int e0 = wave * 64 + t * 16;
        union { bf16x8 v8; nbf e[8]; } af;
        #pragma unroll
        for (int j = 0; j < 8; ++j) af.e[j] = (nbf)0.f;
        if (lq < 2) {
            #pragma unroll
            for (int j = 0; j < 8; ++j) af.e[j] = v_s[lq * 8 + j][e0 + lr];
        }
        f32x4 ov = {0.f, 0.f, 0.f, 0.f};
        ov = __builtin_amdgcn_mfma_f32_16x16x32_bf16(af.v8, pf.v8, ov, 0, 0, 0);
        // lane holds O[l=lr][e0 + lq*4 + r]
        union { unsigned long long u; nbf e[4]; } o4;
        #pragma unroll
        for (int r = 0; r < 4; ++r) o4.e[r] = (nbf)ov[r];
        *(unsigned long long*)(orow + lr * EE + e0 + lq * 4) = o4.u;
    }
}

// ---------------------------------------------------------------------------
// Final attention: one block per node. G rows padded to GST for aligned vec8.
// ---------------------------------------------------------------------------
__global__ __launch_bounds__(256) void final_attn_kernel(const nbf* __restrict__ O,
                const float* __restrict__ T, nbf* __restrict__ G)
{
    const int i = blockIdx.x;
    const int tid = threadIdx.x;
    __shared__ __align__(16) nbf o_s[32][328];
    __shared__ float t_s[644];
    __shared__ float a_lds[32];
    const nbf* orow = O + (long)i * (32 * EE);
    for (int v = tid; v < 32 * 40; v += 256) {
        const int row = v / 40, cv = (v % 40) * 8;
        *(bf16x8*)&o_s[row][cv] = *(const bf16x8*)(orow + row * EE + cv);
    }
    for (int c = tid; c < KF; c += 256) t_s[c] = T[(long)i * KF + c];
    __syncthreads();
    {
        const int m = tid >> 3, sub = tid & 7;
        const int hoff = (m < 16) ? 0 : 320;
        float p = 0.f;
        #pragma unroll
        for (int jc = 0; jc < 5; ++jc) {
            const int e0 = (jc * 8 + sub) * 8;
            bf16x8 ovv = *(const bf16x8*)&o_s[m][e0];
            #pragma unroll
            for (int j = 0; j < 8; ++j) p += (float)ovv[j] * t_s[hoff + e0 + j];
        }
        p += __shfl_down(p, 4, 8);
        p += __shfl_down(p, 2, 8);
        p += __shfl_down(p, 1, 8);
        if (sub == 0) a_lds[m] = (p + t_s[(m < 16) ? 640 : 641]) * 0.05590169943749474f;
    }
    __syncthreads();
    if (tid < 32) {
        float sv = a_lds[tid];
        float mx = sv;
        for (int o = 16; o > 0; o >>= 1) mx = fmaxf(mx, __shfl_xor(mx, o, 32));
        float e = __expf(sv - mx);
        float sm = e;
        for (int o = 16; o > 0; o >>= 1) sm += __shfl_xor(sm, o, 32);
        a_lds[tid] = e / sm;
    }
    __syncthreads();
    nbf* grow = G + (long)i * GST;
    if (tid < 2) {
        float sm = 0.f;
        for (int m = tid * 16; m < tid * 16 + 16; ++m) sm += a_lds[m];
        grow[640 + tid] = (nbf)sm;
    }
    for (int v = tid; v < 80; v += 256) {
        const int half = v / 40, cv = (v % 40) * 8;
        float av[8] = {0.f,0.f,0.f,0.f,0.f,0.f,0.f,0.f};
        #pragma unroll
        for (int m = 0; m < 16; ++m) {
            const float a = a_lds[half * 16 + m];
            bf16x8 ovv = *(const bf16x8*)&o_s[half * 16 + m][cv];
            #pragma unroll
            for (int j = 0; j < 8; ++j) av[j] += a * (float)ovv[j];
        }
        union { bf16x8 v8; nbf e[8]; } u;
        #pragma unroll
        for (int j = 0; j < 8; ++j) u.e[j] = (nbf)av[j];
        *(bf16x8*)(grow + half * 320 + cv) = u.v8;
    }
}

// ---------------------------------------------------------------------------
// out[i,j] = elu( ofin[i,:] @ Wfin[:,j] + bfin[j] ); Wfin cached in LDS
// ---------------------------------------------------------------------------
__global__ __launch_bounds__(256) void out_proj_kernel(const nbf* __restrict__ ofin,
        const float* __restrict__ Wfin, const float* __restrict__ bfin,
        void* __restrict__ out, long obase, int total, const int* __restrict__ flag)
{
    __shared__ float Wf[320][OUTD];
    __shared__ float bf_s[OUTD];
    for (int v = threadIdx.x; v < 320 * OUTD; v += 256) Wf[v / OUTD][v % OUTD] = Wfin[v];
    if (threadIdx.x < OUTD) bf_s[threadIdx.x] = bfin[threadIdx.x];
    __syncthreads();
    const int id = blockIdx.x * 256 + threadIdx.x;
    if (id >= total) return;
    const int i = id / OUTD, j = id % OUTD;
    const bf16x8* row = (const bf16x8*)(ofin + (long)i * EE);
    float acc = bf_s[j];
    #pragma unroll
    for (int cv = 0; cv < 40; ++cv) {
        bf16x8 ovv = row[cv];
        #pragma unroll
        for (int jj = 0; jj < 8; ++jj) acc += (float)ovv[jj] * Wf[cv * 8 + jj][j];
    }
    float r = acc > 0.f ? acc : expm1f(acc);
    if (*flag) ((bf16*)out)[obase + id] = __float2bfloat16(r);
    else       ((float*)out)[obase + id] = r;
}

// ---------------------------------------------------------------------------
extern "C" void kernel_launch(void* const* d_in, const int* in_sizes, int n_in,
                              void* d_out, int out_size, void* d_ws, size_t ws_size,
                              hipStream_t stream)
{
    const int* in_idx  = (const int*)d_in[1];
    const int* out_idx = (const int*)d_in[2];

    char* p = (char*)d_ws;
    auto alloc = [&](size_t bytes) { char* r = p; p += (bytes + 255) & ~(size_t)255; return r; };
    const size_t EE2 = (size_t)EE * EE;
    int*   flag       = (int*)alloc(256);
    nbf*   X_bf       = (nbf*)alloc((size_t)NNODE * EE * 2);
    nbf*   qkvw6_bf   = (nbf*)alloc(6 * EE2 * 2);     // [in q,k,v | out q,k,v]
    nbf*   Wg6_bf     = (nbf*)alloc(6 * EE2 * 2);     // in_Wq..out_Wv
    nbf*   qkvw_fin_bf= (nbf*)alloc(3 * EE2 * 2);
    nbf*   owT        = (nbf*)alloc(3 * EE2 * 2);     // [in^T | out^T | fin^T]
    float* qkvw_fin_f = (float*)alloc(3 * EE2 * 4);
    float* qkvb_fin_f = (float*)alloc(3 * EE * 4);
    float* bcat       = (float*)alloc(PCOLS * 4);
    float* ob_in_f    = (float*)alloc(EE * 4);
    float* ob_out_f   = (float*)alloc(EE * 4);
    float* ob_fin_f   = (float*)alloc(EE * 4);
    float* W_f        = (float*)alloc((size_t)EE * OUTD * 4);
    float* ow_fin_f   = (float*)alloc(EE2 * 4);
    // composed
    nbf*   AcatT  = (nbf*)alloc((size_t)PCOLS * EE * 2);   // [1920][320]
    nbf*   Qc_bf  = (nbf*)alloc(EE2 * 2);
    nbf*   Kcat   = (nbf*)alloc((size_t)KF * EE * 2);      // [642][320]
    float* bqc_in = (float*)alloc(EE * 4);
    nbf*   M2T    = (nbf*)alloc((size_t)KF * EE * 2);      // [642][320]
    float* bT     = (float*)alloc(KF * 4);
    nbf*   VcatT  = (nbf*)alloc((size_t)EE * GST * 2);     // [320][648]
    float* Wfin   = (float*)alloc((size_t)EE * OUTD * 4);
    float* bfin   = (float*)alloc(64 * 4);
    nbf*   P      = (nbf*)alloc((size_t)NNODE * PCOLS * 2);
    size_t fixed = (size_t)(p - (char*)d_ws);

    const size_t per_node = (size_t)32 * EE * 2 + (size_t)KF * 4 + (size_t)GST * 2 + (size_t)EE * 2;
    size_t avail = (ws_size > fixed + 65536) ? (ws_size - fixed - 65536) : 0;
    long chunk_l = (long)(avail / (per_node + 8));
    int chunk = (chunk_l > NNODE) ? NNODE : (chunk_l < 1 ? 1 : (int)chunk_l);
    nbf*   O_c    = (nbf*)alloc((size_t)chunk * 32 * EE * 2);
    float* T_c    = (float*)alloc((size_t)chunk * KF * 4);
    nbf*   G_c    = (nbf*)alloc((size_t)chunk * GST * 2);
    nbf*   ofin_c = (nbf*)alloc((size_t)chunk * EE * 2);

    dim3 blk(256);
    // ---- detect dtype + normalize inputs ----
    detect_dtype_kernel<<<1, blk, 0, stream>>>((const unsigned int*)d_in[0], flag);
    convert_bf_kernel<<<(NNODE * EE + 255) / 256, blk, 0, stream>>>(d_in[0], X_bf, NNODE * EE, flag);
    ConvTab ct;
    int s = 0;
    auto seg = [&](const void* src, void* dst, int n, int tobf) {
        ct.src[s] = src; ct.dst[s] = dst; ct.n[s] = n; ct.tobf[s] = tobf; ++s;
    };
    seg(d_in[6],  qkvw6_bf,           (int)(3 * EE2), 1);
    seg(d_in[13], qkvw6_bf + 3 * EE2, (int)(3 * EE2), 1);
    seg(d_in[3],  Wg6_bf + 0 * EE2, (int)EE2, 1);
    seg(d_in[4],  Wg6_bf + 1 * EE2, (int)EE2, 1);
    seg(d_in[5],  Wg6_bf + 2 * EE2, (int)EE2, 1);
    seg(d_in[10], Wg6_bf + 3 * EE2, (int)EE2, 1);
    seg(d_in[11], Wg6_bf + 4 * EE2, (int)EE2, 1);
    seg(d_in[12], Wg6_bf + 5 * EE2, (int)EE2, 1);
    seg(d_in[17], qkvw_fin_bf, (int)(3 * EE2), 1);
    seg(d_in[17], qkvw_fin_f,  (int)(3 * EE2), 0);
    seg(d_in[18], qkvb_fin_f, 3 * EE, 0);
    seg(d_in[7],  bcat,       3 * EE, 0);
    seg(d_in[14], bcat + 960, 3 * EE, 0);
    seg(d_in[9],  ob_in_f,  EE, 0);
    seg(d_in[16], ob_out_f, EE, 0);
    seg(d_in[20], ob_fin_f, EE, 0);
    seg(d_in[21], W_f, EE * OUTD, 0);
    seg(d_in[19], ow_fin_f, (int)EE2, 0);
    convert_batch_kernel<<<dim3((3 * (int)EE2 + 255) / 256, NSEG), blk, 0, stream>>>(ct, flag);
    transpose3_kernel<<<dim3(10, 10, 3), blk, 0, stream>>>(d_in[8], d_in[15], d_in[19], owT, flag);

    // ---- compose (all MFMA, bf16) ----
    // AcatT[g] = qkvw6[g] @ Wg6[g]^T   (z-batched)
    gemm_mfma<bf16><<<dim3(3, 3, 6), blk, 0, stream>>>(
        qkvw6_bf, EE, Wg6_bf, EE, nullptr, (bf16*)AcatT, EE, EE, EE, EE,
        (long)EE2, (long)EE2, (long)EE2);
    // Qc = owT_in @ wqf^T
    gemm_mfma<bf16><<<dim3(3, 3, 1), blk, 0, stream>>>(
        owT, EE, qkvw_fin_bf, EE, nullptr, (bf16*)Qc_bf, EE, EE, EE, EE, 0, 0, 0);
    // Kcat rows 0-319 / 320-639 = owT_{in,out} @ wkf^T  (z-batched)
    gemm_mfma<bf16><<<dim3(3, 3, 2), blk, 0, stream>>>(
        owT, EE, qkvw_fin_bf + (size_t)320 * EE, EE, nullptr, (bf16*)Kcat, EE, EE, EE, EE,
        (long)EE2, 0, (long)320 * EE);
    // VcatT cols 0-319 / 320-639 = wvf @ owT_{in,out}^T  (z-batched)
    gemm_mfma<bf16><<<dim3(3, 3, 2), blk, 0, stream>>>(
        qkvw_fin_bf + (size_t)640 * EE, EE, owT, EE, nullptr, (bf16*)VcatT, GST, EE, EE, EE,
        0, (long)EE2, 320);
    compose_bias_kernel<<<5, 320, 0, stream>>>(ob_in_f, ob_out_f, qkvw_fin_f, qkvb_fin_f,
                                               bqc_in, Kcat, VcatT);
    // M2T = Kcat @ Qc^T
    gemm_mfma<bf16><<<dim3(3, 6, 1), blk, 0, stream>>>(
        Kcat, EE, Qc_bf, EE, nullptr, (bf16*)M2T, EE, KF, EE, EE, 0, 0, 0);
    compose_bT<<<3, blk, 0, stream>>>(bqc_in, Kcat, bT);
    gemm_k<true, false, float><<<dim3(1, 5), blk, 0, stream>>>(
        ow_fin_f, EE, W_f, OUTD, nullptr, Wfin, OUTD, EE, OUTD, EE);
    compose_bfin<<<1, 64, 0, stream>>>(ob_fin_f, W_f, bfin);

    // ---- P = X @ Acat + bcat  (MFMA) ----
    gemm_mfma<bf16><<<dim3(PCOLS / 128, (NNODE + 127) / 128), blk, 0, stream>>>(
        X_bf, EE, AcatT, EE, bcat, (bf16*)P, PCOLS, NNODE, PCOLS, EE, 0, 0, 0);

    // ---- per-node pipeline (chunked) ----
    for (int base = 0; base < NNODE; base += chunk) {
        int cnt = (NNODE - base < chunk) ? (NNODE - base) : chunk;
        attn1_kernel<<<2 * cnt, dim3(320), 0, stream>>>(P, in_idx, out_idx, O_c, base);
        gemm_mfma<float><<<dim3((KF + 127) / 128, (cnt + 127) / 128), blk, 0, stream>>>(
            O_c, 32 * EE, M2T, EE, bT, T_c, KF, cnt, KF, EE, 0, 0, 0);
        final_attn_kernel<<<cnt, blk, 0, stream>>>(O_c, T_c, G_c);
        gemm_mfma<bf16><<<dim3((EE + 127) / 128, (cnt + 127) / 128), blk, 0, stream>>>(
            G_c, GST, VcatT, GST, nullptr, (bf16*)ofin_c, EE, cnt, EE, KF, 0, 0, 0);
        out_proj_kernel<<<(cnt * OUTD + 255) / 256, blk, 0, stream>>>(
            ofin_c, Wfin, bfin, d_out, (long)base * OUTD, cnt * OUTD, flag);
    }
}